// Round 12
// baseline (361.506 us; speedup 1.0000x reference)
//
#include <hip/hip_runtime.h>

#define F_IN 128
#define NBMAX 512      // max coarse buckets (256 nodes each)
#define TILE1 4096     // edges per partition tile (782 blocks -> 3/CU)

typedef __attribute__((ext_vector_type(8))) short short8;
typedef __attribute__((ext_vector_type(4))) float f32x4;

__device__ __forceinline__ unsigned short f2bf(float f) {   // RNE float->bf16
    unsigned u = __float_as_uint(f);
    u += 0x7fffu + ((u >> 16) & 1u);
    return (unsigned short)(u >> 16);
}
__device__ __forceinline__ float bflo(unsigned u) { return __uint_as_float(u << 16); }
__device__ __forceinline__ float bfhi(unsigned u) { return __uint_as_float(u & 0xffff0000u); }

// ---- fold constants + zero bcnt/done (launched FIRST) ----
__global__ __launch_bounds__(256) void k_wfold(const float* __restrict__ W2,
                                               const float* __restrict__ b2,
                                               const float* __restrict__ Wl1,
                                               const float* __restrict__ bl1,
                                               const float* __restrict__ Wl2,
                                               const float* __restrict__ bl2,
                                               float* __restrict__ Wfold,
                                               float* __restrict__ bconst,
                                               int* __restrict__ bcnt,
                                               int* __restrict__ done) {
    __shared__ float Wc[64][2];
    __shared__ float bc0[2];
    int t = threadIdx.x;
    for (int i = t; i < NBMAX; i += 256) bcnt[i] = 0;
    if (t == 0) *done = 0;
    if (t < 128) {
        int k = t >> 1, c = t & 1;
        float s = 0.f;
        for (int m = 0; m < 32; ++m) s += Wl1[k * 32 + m] * Wl2[m * 2 + c];
        Wc[k][c] = s;
    } else if (t < 130) {
        int c = t - 128;
        float s = bl2[c];
        for (int m = 0; m < 32; ++m) s += bl1[m] * Wl2[m * 2 + c];
        bc0[c] = s;
    }
    __syncthreads();
    if (t < 128) {
        int k = t >> 1, c = t & 1;
        float s = 0.f;
        for (int j = 0; j < 64; ++j) s += W2[k * 64 + j] * Wc[j][c];
        Wfold[k * 2 + c] = s;
    } else if (t < 130) {
        int c = t - 128;
        float s = bc0[c];
        for (int j = 0; j < 64; ++j) s += b2[j] * Wc[j][c];
        bconst[c] = s;
    }
}

// ---- coarse-bucket histogram, grid-stride (1024 blocks) ----
__global__ __launch_bounds__(256) void k_cnt(const int* __restrict__ dst, int E,
                                             int* __restrict__ bcnt, int nb) {
    __shared__ int h[NBMAX];
    int t = threadIdx.x;
    for (int i = t; i < nb; i += 256) h[i] = 0;
    __syncthreads();
    int stride = gridDim.x * 256;
    for (int i = blockIdx.x * 256 + t; i < E; i += stride)
        atomicAdd(&h[dst[i] >> 8], 1);
    __syncthreads();
    for (int i = t; i < nb; i += 256)
        if (h[i]) atomicAdd(&bcnt[i], h[i]);
}

// ---- exclusive scan of bucket counts (nb <= 512), single block ----
__global__ __launch_bounds__(512) void k_bscan1(const int* __restrict__ bcnt,
                                                int* __restrict__ boff,
                                                int* __restrict__ cursor, int nb) {
    __shared__ int part[512];
    int t = threadIdx.x;
    int v = (t < nb) ? bcnt[t] : 0;
    part[t] = v;
    __syncthreads();
    for (int d = 1; d < 512; d <<= 1) {
        int u = (t >= d) ? part[t - d] : 0;
        __syncthreads();
        part[t] += u;
        __syncthreads();
    }
    if (t < nb) { boff[t] = part[t] - v; cursor[t] = part[t] - v; }
    if (t == 511) boff[nb] = part[511];   // == E
}

// ---- pass 1: LDS-staged partition into coarse buckets; wave-per-bucket output ----
__global__ __launch_bounds__(256) void k_part1(const int* __restrict__ src,
                                               const int* __restrict__ dst,
                                               int* __restrict__ cursor,
                                               unsigned* __restrict__ ebuf,
                                               int E, int nb) {
    __shared__ unsigned staged[TILE1];                               // 16 KB
    __shared__ int hist[NBMAX], lbase[NBMAX], lcur[NBMAX], gbase[NBMAX];  // 8 KB
    int t = threadIdx.x;
    for (int i = t; i < nb; i += 256) hist[i] = 0;
    __syncthreads();
    int base = blockIdx.x * TILE1;
    int end = min(base + TILE1, E);
    for (int i = base + t; i < end; i += 256)
        atomicAdd(&hist[dst[i] >> 8], 1);
    __syncthreads();
    if (t < 64) {                                // single-wave chunked scan
        int carry = 0;
        for (int c = 0; c < (nb + 63) / 64; ++c) {
            int idx = c * 64 + t;
            int v = (idx < nb) ? hist[idx] : 0;
            int inc = v;
            for (int d = 1; d < 64; d <<= 1) {
                int u = __shfl_up(inc, d, 64);
                if (t >= d) inc += u;
            }
            if (idx < nb) { int ex = carry + inc - v; lbase[idx] = ex; lcur[idx] = ex; }
            carry += __shfl(inc, 63, 64);
        }
    }
    __syncthreads();
    for (int i = t; i < nb; i += 256)
        gbase[i] = hist[i] ? atomicAdd(&cursor[i], hist[i]) : 0;
    for (int i = base + t; i < end; i += 256) {
        int d = dst[i];
        int b = d >> 8;
        int r = atomicAdd(&lcur[b], 1);
        staged[r] = ((unsigned)src[i] << 8) | (unsigned)(d & 255);
    }
    __syncthreads();
    // output: wave wv handles buckets wv, wv+4, ... (runs avg TILE1/nb entries)
    int wv = t >> 6, lane = t & 63;
    for (int b = wv; b < nb; b += 4) {
        int lo = lbase[b], hi = lcur[b], gb = gbase[b];
        for (int i = lo + lane; i < hi; i += 64)
            ebuf[gb + (i - lo)] = staged[i];
    }
}

// ---- pass 2: per-bucket 256-bin counting sort; direct writes into the block's
// exclusive ~32KB csr window (L2-hot, no staging); 1024 thr for latency hiding ----
__global__ __launch_bounds__(1024) void k_part2(const unsigned* __restrict__ ebuf,
                                                const int* __restrict__ boff,
                                                int* __restrict__ csr,
                                                int* __restrict__ offs,
                                                float* __restrict__ dinv, int n) {
    __shared__ int hist[256], lcur[256];
    int t = threadIdx.x;
    int b = blockIdx.x;
    int beg = boff[b], end = boff[b + 1];
    if (t < 256) hist[t] = 0;
    __syncthreads();
    for (int i = beg + t; i < end; i += 1024)
        atomicAdd(&hist[ebuf[i] & 255u], 1);
    __syncthreads();
    if (t < 64) {
        int carry = 0;
        for (int c = 0; c < 4; ++c) {
            int idx = c * 64 + t;
            int v = hist[idx];
            int inc = v;
            for (int d = 1; d < 64; d <<= 1) {
                int u = __shfl_up(inc, d, 64);
                if (t >= d) inc += u;
            }
            int ex = carry + inc - v;
            lcur[idx] = ex;
            int node = b * 256 + idx;
            if (node <= n) offs[node] = beg + ex;
            if (node < n) dinv[node] = rsqrtf((float)(v + 1));
            carry += __shfl(inc, 63, 64);
        }
    }
    __syncthreads();
    for (int i = beg + t; i < end; i += 1024) {
        unsigned e = ebuf[i];
        int r = atomicAdd(&lcur[(int)(e & 255u)], 1);
        csr[beg + r] = (int)(e >> 8);
    }
}

// ---- MFMA GEMM: G[n][64](bf16) = (X[n][K] @ W[K][64]) * dinv[n] ----
template<int K, bool INBF16>
__global__ __launch_bounds__(256) void k_gemm_mfma(const void* __restrict__ Xv,
                                                   const float* __restrict__ W,
                                                   const float* __restrict__ dinv,
                                                   unsigned short* __restrict__ G, int n) {
    constexpr int AST = K + 8;
    __shared__ unsigned short A_lds[64 * AST];
    __shared__ unsigned short Wt_lds[64 * AST];
    __shared__ unsigned short C_lds[64 * 72];
    int t = threadIdx.x;
    int base = blockIdx.x * 64;

    for (int idx = t; idx < K * 64; idx += 256) {
        int k = idx >> 6, nn = idx & 63;
        Wt_lds[nn * AST + k] = f2bf(W[idx]);
    }
    if (!INBF16) {
        const f32x4* X4 = (const f32x4*)Xv;
        constexpr int F4 = K / 4;
        for (int idx = t; idx < 64 * F4; idx += 256) {
            int row = idx / F4, c4 = idx % F4;
            f32x4 f = {0.f, 0.f, 0.f, 0.f};
            if (base + row < n) f = X4[(size_t)base * F4 + idx];
            unsigned p0 = (unsigned)f2bf(f.x) | ((unsigned)f2bf(f.y) << 16);
            unsigned p1 = (unsigned)f2bf(f.z) | ((unsigned)f2bf(f.w) << 16);
            *(uint2*)&A_lds[row * AST + c4 * 4] = make_uint2(p0, p1);
        }
    } else {
        const unsigned* H32 = (const unsigned*)Xv;
        constexpr int U2 = K / 2;
        for (int idx = t; idx < 64 * U2; idx += 256) {
            int row = idx / U2, c2 = idx % U2;
            unsigned u = 0;
            if (base + row < n) u = H32[(size_t)base * U2 + idx];
            *(unsigned*)&A_lds[row * AST + c2 * 2] = u;
        }
    }
    __syncthreads();

    int lane = t & 63, w = t >> 6;
    int q = lane >> 4, m = lane & 15;
    f32x4 acc0 = {0,0,0,0}, acc1 = {0,0,0,0}, acc2 = {0,0,0,0}, acc3 = {0,0,0,0};
    const unsigned short* arow = &A_lds[(16 * w + m) * AST + q * 8];
#pragma unroll
    for (int s = 0; s < K / 32; ++s) {
        short8 a  = *(const short8*)(arow + s * 32);
        short8 w0 = *(const short8*)&Wt_lds[ m       * AST + s * 32 + q * 8];
        short8 w1 = *(const short8*)&Wt_lds[(16 + m) * AST + s * 32 + q * 8];
        short8 w2 = *(const short8*)&Wt_lds[(32 + m) * AST + s * 32 + q * 8];
        short8 w3 = *(const short8*)&Wt_lds[(48 + m) * AST + s * 32 + q * 8];
        acc0 = __builtin_amdgcn_mfma_f32_16x16x32_bf16(a, w0, acc0, 0, 0, 0);
        acc1 = __builtin_amdgcn_mfma_f32_16x16x32_bf16(a, w1, acc1, 0, 0, 0);
        acc2 = __builtin_amdgcn_mfma_f32_16x16x32_bf16(a, w2, acc2, 0, 0, 0);
        acc3 = __builtin_amdgcn_mfma_f32_16x16x32_bf16(a, w3, acc3, 0, 0, 0);
    }
    float dv[4];
#pragma unroll
    for (int r = 0; r < 4; ++r) {
        int node = base + 16 * w + q * 4 + r;
        dv[r] = (node < n) ? dinv[node] : 0.f;
    }
#pragma unroll
    for (int r = 0; r < 4; ++r) {
        int row = 16 * w + q * 4 + r;
        C_lds[row * 72 + m]      = f2bf(acc0[r] * dv[r]);
        C_lds[row * 72 + 16 + m] = f2bf(acc1[r] * dv[r]);
        C_lds[row * 72 + 32 + m] = f2bf(acc2[r] * dv[r]);
        C_lds[row * 72 + 48 + m] = f2bf(acc3[r] * dv[r]);
    }
    __syncthreads();
    for (int idx = t; idx < 4096; idx += 256) {
        int row = idx >> 6, col = idx & 63;
        int node = base + row;
        if (node < n) G[(size_t)node * 64 + col] = C_lds[row * 72 + col];
    }
}

// ---- gather-1 + fused fold; csr indices software-pipelined one iter ahead ----
__global__ __launch_bounds__(256) void k_gfold(const int* __restrict__ csr,
                                               const int* __restrict__ offs,
                                               const unsigned short* __restrict__ G,
                                               const float* __restrict__ dinv,
                                               const float* __restrict__ bias,
                                               const float* __restrict__ Wfold,
                                               float2* __restrict__ P, int n) {
    int w = (blockIdx.x * 256 + threadIdx.x) >> 6;
    if (w >= n) return;
    int lane = threadIdx.x & 63;
    int half = lane >> 5, sl = lane & 31;
    const unsigned* Gp = (const unsigned*)G;        // 32 dwords (64 bf16) per row
    float a0 = 0.f, a1 = 0.f;
    if (half == 0) {                                 // self-loop row
        unsigned u = Gp[(size_t)w * 32 + sl];
        a0 = bflo(u); a1 = bfhi(u);
    }
    int beg = offs[w], end = offs[w + 1];
    int e = beg;
    int c0 = 0, c1 = 0, c2 = 0, c3 = 0, c4 = 0, c5 = 0, c6 = 0, c7 = 0;
    if (e + 16 <= end) {
        c0 = csr[e + half];      c1 = csr[e + 2 + half];
        c2 = csr[e + 4 + half];  c3 = csr[e + 6 + half];
        c4 = csr[e + 8 + half];  c5 = csr[e + 10 + half];
        c6 = csr[e + 12 + half]; c7 = csr[e + 14 + half];
    }
    while (e + 16 <= end) {                          // 16 edges: 8 indep row loads
        unsigned u0 = Gp[(size_t)c0 * 32 + sl];
        unsigned u1 = Gp[(size_t)c1 * 32 + sl];
        unsigned u2 = Gp[(size_t)c2 * 32 + sl];
        unsigned u3 = Gp[(size_t)c3 * 32 + sl];
        unsigned u4 = Gp[(size_t)c4 * 32 + sl];
        unsigned u5 = Gp[(size_t)c5 * 32 + sl];
        unsigned u6 = Gp[(size_t)c6 * 32 + sl];
        unsigned u7 = Gp[(size_t)c7 * 32 + sl];
        int ne = e + 16;
        if (ne + 16 <= end) {                        // prefetch next iter's csr
            c0 = csr[ne + half];      c1 = csr[ne + 2 + half];
            c2 = csr[ne + 4 + half];  c3 = csr[ne + 6 + half];
            c4 = csr[ne + 8 + half];  c5 = csr[ne + 10 + half];
            c6 = csr[ne + 12 + half]; c7 = csr[ne + 14 + half];
        }
        a0 += ((bflo(u0) + bflo(u1)) + (bflo(u2) + bflo(u3)))
            + ((bflo(u4) + bflo(u5)) + (bflo(u6) + bflo(u7)));
        a1 += ((bfhi(u0) + bfhi(u1)) + (bfhi(u2) + bfhi(u3)))
            + ((bfhi(u4) + bfhi(u5)) + (bfhi(u6) + bfhi(u7)));
        e = ne;
    }
    for (; e + 8 <= end; e += 8) {                   // 8-edge step (4 loads)
        int s0 = csr[e + half],     s1 = csr[e + 2 + half];
        int s2 = csr[e + 4 + half], s3 = csr[e + 6 + half];
        unsigned u0 = Gp[(size_t)s0 * 32 + sl];
        unsigned u1 = Gp[(size_t)s1 * 32 + sl];
        unsigned u2 = Gp[(size_t)s2 * 32 + sl];
        unsigned u3 = Gp[(size_t)s3 * 32 + sl];
        a0 += (bflo(u0) + bflo(u1)) + (bflo(u2) + bflo(u3));
        a1 += (bfhi(u0) + bfhi(u1)) + (bfhi(u2) + bfhi(u3));
    }
    for (; e + 2 <= end; e += 2) {
        int s = csr[e + half];
        unsigned u = Gp[(size_t)s * 32 + sl];
        a0 += bflo(u); a1 += bfhi(u);
    }
    if (e < end && half == 0) {                      // odd last edge
        int s = csr[e];
        unsigned u = Gp[(size_t)s * 32 + sl];
        a0 += bflo(u); a1 += bfhi(u);
    }
    a0 += __shfl_xor(a0, 32, 64);                    // merge halves
    a1 += __shfl_xor(a1, 32, 64);
    float d = dinv[w];
    float2 bb = ((const float2*)bias)[sl];
    float v0 = fmaxf(fmaf(a0, d, bb.x), 0.f);        // H1[w][2sl]
    float v1 = fmaxf(fmaf(a1, d, bb.y), 0.f);        // H1[w][2sl+1]
    float4 wf = ((const float4*)Wfold)[sl];
    float px = v0 * wf.x + v1 * wf.z;
    float py = v0 * wf.y + v1 * wf.w;
#pragma unroll
    for (int m = 16; m >= 1; m >>= 1) {
        px += __shfl_xor(px, m, 64);
        py += __shfl_xor(py, m, 64);
    }
    if (lane == 0) P[w] = make_float2(px * d, py * d);
}

// ---- gather-2 on P (N x 2, L2-resident) ----
__global__ __launch_bounds__(256) void k_gather2(const int* __restrict__ csr,
                                                 const int* __restrict__ offs,
                                                 const float2* __restrict__ P,
                                                 const float* __restrict__ dinv,
                                                 const float* __restrict__ bconst,
                                                 float* __restrict__ logits, int n) {
    int w = (blockIdx.x * 256 + threadIdx.x) >> 6;
    if (w >= n) return;
    int lane = threadIdx.x & 63;
    int beg = offs[w], end = offs[w + 1];
    float ax = 0.f, ay = 0.f;
    for (int i = beg + lane; i < end; i += 64) {
        float2 p = P[csr[i]];
        ax += p.x; ay += p.y;
    }
#pragma unroll
    for (int m = 32; m >= 1; m >>= 1) {
        ax += __shfl_xor(ax, m, 64);
        ay += __shfl_xor(ay, m, 64);
    }
    if (lane == 0) {
        float2 self = P[w];
        float d = dinv[w];
        logits[w * 2]     = d * (self.x + ax) + bconst[0];
        logits[w * 2 + 1] = d * (self.y + ay) + bconst[1];
    }
}

// ---- softmax stage 1 + fused last-block combine ----
__global__ __launch_bounds__(256) void k_sm_part(const float* __restrict__ logits,
                                                 float4* __restrict__ partials,
                                                 float4* __restrict__ glob,
                                                 int* __restrict__ done, int n) {
    __shared__ float r0[256], r1[256];
    __shared__ int last;
    int t = threadIdx.x;
    int i = blockIdx.x * 256 + t;
    float l0 = -3.4e38f, l1 = -3.4e38f;
    if (i < n) { l0 = logits[i * 2]; l1 = logits[i * 2 + 1]; }
    r0[t] = l0; r1[t] = l1;
    __syncthreads();
    for (int s = 128; s > 0; s >>= 1) {
        if (t < s) { r0[t] = fmaxf(r0[t], r0[t + s]); r1[t] = fmaxf(r1[t], r1[t + s]); }
        __syncthreads();
    }
    float m0 = r0[0], m1 = r1[0];
    __syncthreads();
    r0[t] = (i < n) ? __expf(l0 - m0) : 0.f;
    r1[t] = (i < n) ? __expf(l1 - m1) : 0.f;
    __syncthreads();
    for (int s = 128; s > 0; s >>= 1) {
        if (t < s) { r0[t] += r0[t + s]; r1[t] += r1[t + s]; }
        __syncthreads();
    }
    if (t == 0) partials[blockIdx.x] = make_float4(m0, r0[0], m1, r1[0]);
    __threadfence();
    if (t == 0) last = (atomicAdd(done, 1) == (int)gridDim.x - 1);
    __syncthreads();
    if (!last) return;
    __threadfence();                                 // acquire partials
    int nb = gridDim.x;
    float M0l = -3.4e38f, M1l = -3.4e38f;
    for (int k = t; k < nb; k += 256) {
        float4 p = partials[k];
        M0l = fmaxf(M0l, p.x); M1l = fmaxf(M1l, p.z);
    }
    __syncthreads();
    r0[t] = M0l; r1[t] = M1l;
    __syncthreads();
    for (int s = 128; s > 0; s >>= 1) {
        if (t < s) { r0[t] = fmaxf(r0[t], r0[t + s]); r1[t] = fmaxf(r1[t], r1[t + s]); }
        __syncthreads();
    }
    float M0 = r0[0], M1 = r1[0];
    __syncthreads();
    float s0 = 0.f, s1 = 0.f;
    for (int k = t; k < nb; k += 256) {
        float4 p = partials[k];
        s0 += p.y * __expf(p.x - M0);
        s1 += p.w * __expf(p.z - M1);
    }
    r0[t] = s0; r1[t] = s1;
    __syncthreads();
    for (int s = 128; s > 0; s >>= 1) {
        if (t < s) { r0[t] += r0[t + s]; r1[t] += r1[t + s]; }
        __syncthreads();
    }
    if (t == 0) *glob = make_float4(M0, 1.f / r0[0], M1, 1.f / r1[0]);
}

// ---- softmax stage 2: normalize ----
__global__ __launch_bounds__(256) void k_sm_final(const float* __restrict__ logits,
                                                  const float4* __restrict__ glob,
                                                  float* __restrict__ out, int n) {
    int i = blockIdx.x * 256 + threadIdx.x;
    if (i < n) {
        float4 g = *glob;
        out[i * 2]     = __expf(logits[i * 2]     - g.x) * g.y;
        out[i * 2 + 1] = __expf(logits[i * 2 + 1] - g.z) * g.w;
    }
}

extern "C" void kernel_launch(void* const* d_in, const int* in_sizes, int n_in,
                              void* d_out, int out_size, void* d_ws, size_t ws_size,
                              hipStream_t stream) {
    const float* x   = (const float*)d_in[0];
    const int*   ei  = (const int*)d_in[1];
    const float* W1  = (const float*)d_in[2];
    const float* b1  = (const float*)d_in[3];
    const float* W2  = (const float*)d_in[4];
    const float* b2  = (const float*)d_in[5];
    const float* Wl1 = (const float*)d_in[6];
    const float* bl1 = (const float*)d_in[7];
    const float* Wl2 = (const float*)d_in[8];
    const float* bl2 = (const float*)d_in[9];
    float* out = (float*)d_out;

    int N = in_sizes[0] / F_IN;   // 100000
    int E = in_sizes[1] / 2;      // 3200000
    const int* esrc = ei;
    const int* edst = ei + E;

    int nbuck = (N + 255) / 256;  // 391 coarse buckets of 256 nodes

    char* ws = (char*)d_ws;
    size_t off = 0;
    auto alloc = [&](size_t bytes) { void* p = ws + off; off += (bytes + 255) & ~(size_t)255; return p; };
    int*            bcnt   = (int*)alloc((size_t)NBMAX * 4);
    int*            boff   = (int*)alloc((size_t)(NBMAX + 1) * 4);
    int*            cursor = (int*)alloc((size_t)NBMAX * 4);
    float*          dinv   = (float*)alloc((size_t)N * 4);
    int*            offs   = (int*)alloc((size_t)(N + 1) * 4);
    int*            csr    = (int*)alloc((size_t)E * 4);                 // 12.8 MB
    unsigned*       ebuf   = (unsigned*)alloc((size_t)E * 4);            // 12.8 MB
    unsigned short* gbuf   = (unsigned short*)alloc((size_t)N * 64 * 2); // 12.8 MB bf16
    float*          Wfold  = (float*)alloc(64 * 2 * 4);
    float*          bconst = (float*)alloc(2 * 4);
    float2*         P      = (float2*)alloc((size_t)N * 8);              // 800 KB
    float*          logits = (float*)alloc((size_t)N * 2 * 4);           // 800 KB
    float4*         smpart = (float4*)alloc((size_t)NBMAX * 16);
    float4*         smglob = (float4*)alloc(16);
    int*            smdone = (int*)alloc(16);

    int tiles = (E + TILE1 - 1) / TILE1;   // 782
    int mb = (N + 63) / 64;
    int wb = (N * 64 + 255) / 256;         // wave-per-node grids
    int nb = (N + 255) / 256;

    // constant folding + zero bcnt/done (first: everything downstream depends)
    k_wfold<<<1, 256, 0, stream>>>(W2, b2, Wl1, bl1, Wl2, bl2, Wfold, bconst, bcnt, smdone);

    // CSR build
    k_cnt<<<1024, 256, 0, stream>>>(edst, E, bcnt, nbuck);
    k_bscan1<<<1, 512, 0, stream>>>(bcnt, boff, cursor, nbuck);
    k_part1<<<tiles, 256, 0, stream>>>(esrc, edst, cursor, ebuf, E, nbuck);
    k_part2<<<nbuck, 1024, 0, stream>>>(ebuf, boff, csr, offs, dinv, N);

    // layer 1 GEMM: G1 = bf16((x@W1)*dinv)
    k_gemm_mfma<128, false><<<mb, 256, 0, stream>>>(x, W1, dinv, gbuf, N);

    // gather-1 + relu + fold: P = dinv * (relu(dinv*(G1[d]+sum G1[src]) + b1) @ Wfold)
    k_gfold<<<wb, 256, 0, stream>>>(csr, offs, gbuf, dinv, b1, Wfold, P, N);

    // gather-2 on P -> logits
    k_gather2<<<wb, 256, 0, stream>>>(csr, offs, P, dinv, bconst, logits, N);

    // softmax (stage1 + fused combine, then normalize)
    k_sm_part<<<nb, 256, 0, stream>>>(logits, smpart, smglob, smdone, N);
    k_sm_final<<<nb, 256, 0, stream>>>(logits, smglob, out, N);
}

// Round 13
// 289.987 us; speedup vs baseline: 1.2466x; 1.2466x over previous
//
#include <hip/hip_runtime.h>

#define F_IN 128
#define NBMAX 512      // max coarse buckets (256 nodes each)
#define TILE1 8192     // edges per partition tile
#define CAP2 10240     // pass-2 LDS staging capacity

typedef __attribute__((ext_vector_type(8))) short short8;
typedef __attribute__((ext_vector_type(4))) float f32x4;

__device__ __forceinline__ unsigned short f2bf(float f) {   // RNE float->bf16
    unsigned u = __float_as_uint(f);
    u += 0x7fffu + ((u >> 16) & 1u);
    return (unsigned short)(u >> 16);
}
__device__ __forceinline__ float bflo(unsigned u) { return __uint_as_float(u << 16); }
__device__ __forceinline__ float bfhi(unsigned u) { return __uint_as_float(u & 0xffff0000u); }

// ---- coarse-bucket histogram: bcnt[dst>>8] += 1, LDS-staged ----
__global__ __launch_bounds__(256) void k_cnt(const int* __restrict__ dst, int E,
                                             int* __restrict__ bcnt, int nb) {
    __shared__ int h[NBMAX];
    int t = threadIdx.x;
    for (int i = t; i < nb; i += 256) h[i] = 0;
    __syncthreads();
    int base = blockIdx.x * TILE1;
    int end = min(base + TILE1, E);
    for (int i = base + t; i < end; i += 256)
        atomicAdd(&h[dst[i] >> 8], 1);
    __syncthreads();
    for (int i = t; i < nb; i += 256)
        if (h[i]) atomicAdd(&bcnt[i], h[i]);
}

// ---- exclusive scan of bucket counts (nb <= 512), single block ----
__global__ __launch_bounds__(512) void k_bscan1(const int* __restrict__ bcnt,
                                                int* __restrict__ boff,
                                                int* __restrict__ cursor, int nb) {
    __shared__ int part[512];
    int t = threadIdx.x;
    int v = (t < nb) ? bcnt[t] : 0;
    part[t] = v;
    __syncthreads();
    for (int d = 1; d < 512; d <<= 1) {
        int u = (t >= d) ? part[t - d] : 0;
        __syncthreads();
        part[t] += u;
        __syncthreads();
    }
    if (t < nb) { boff[t] = part[t] - v; cursor[t] = part[t] - v; }
    if (t == 511) boff[nb] = part[511];   // == E
}

// ---- pass 1: LDS-staged partition into coarse buckets; burst writes ----
// 512 threads: grid is ~1.5 blocks/CU, so waves/block is the parallelism lever
__global__ __launch_bounds__(512) void k_part1(const int* __restrict__ src,
                                               const int* __restrict__ dst,
                                               int* __restrict__ cursor,
                                               unsigned* __restrict__ ebuf,
                                               int E, int nb) {
    __shared__ unsigned staged[TILE1];
    __shared__ unsigned short sbuck[TILE1];
    __shared__ int hist[NBMAX], lbase[NBMAX], lcur[NBMAX], gbase[NBMAX];
    int t = threadIdx.x;
    for (int i = t; i < nb; i += 512) hist[i] = 0;
    __syncthreads();
    int base = blockIdx.x * TILE1;
    int end = min(base + TILE1, E);
    for (int i = base + t; i < end; i += 512)
        atomicAdd(&hist[dst[i] >> 8], 1);
    __syncthreads();
    if (t < 64) {
        int carry = 0;
        for (int c = 0; c < (nb + 63) / 64; ++c) {
            int idx = c * 64 + t;
            int v = (idx < nb) ? hist[idx] : 0;
            int inc = v;
            for (int d = 1; d < 64; d <<= 1) {
                int u = __shfl_up(inc, d, 64);
                if (t >= d) inc += u;
            }
            if (idx < nb) { int ex = carry + inc - v; lbase[idx] = ex; lcur[idx] = ex; }
            carry += __shfl(inc, 63, 64);
        }
    }
    __syncthreads();
    for (int i = t; i < nb; i += 512)
        gbase[i] = hist[i] ? atomicAdd(&cursor[i], hist[i]) : 0;
    for (int i = base + t; i < end; i += 512) {
        int d = dst[i];
        int b = d >> 8;
        int r = atomicAdd(&lcur[b], 1);
        staged[r] = ((unsigned)src[i] << 8) | (unsigned)(d & 255);
        sbuck[r] = (unsigned short)b;
    }
    __syncthreads();
    int cnt = end - base;
    for (int i = t; i < cnt; i += 512) {
        int b = sbuck[i];
        ebuf[gbase[b] + (i - lbase[b])] = staged[i];
    }
}

// ---- pass 2: per-bucket 256-bin counting sort; emits csr, offs, dinv ----
__global__ __launch_bounds__(512) void k_part2(const unsigned* __restrict__ ebuf,
                                               const int* __restrict__ boff,
                                               int* __restrict__ csr,
                                               int* __restrict__ offs,
                                               float* __restrict__ dinv, int n) {
    __shared__ unsigned staged[CAP2];
    __shared__ int hist[256], lcur[256];
    int t = threadIdx.x;
    int b = blockIdx.x;
    int beg = boff[b], end = boff[b + 1];
    int cnt = end - beg;
    if (t < 256) hist[t] = 0;
    __syncthreads();
    for (int i = beg + t; i < end; i += 512)
        atomicAdd(&hist[ebuf[i] & 255u], 1);
    __syncthreads();
    if (t < 64) {
        int carry = 0;
        for (int c = 0; c < 4; ++c) {
            int idx = c * 64 + t;
            int v = hist[idx];
            int inc = v;
            for (int d = 1; d < 64; d <<= 1) {
                int u = __shfl_up(inc, d, 64);
                if (t >= d) inc += u;
            }
            int ex = carry + inc - v;
            lcur[idx] = ex;
            int node = b * 256 + idx;
            if (node <= n) offs[node] = beg + ex;
            if (node < n) dinv[node] = rsqrtf((float)(v + 1));
            carry += __shfl(inc, 63, 64);
        }
    }
    __syncthreads();
    if (cnt <= CAP2) {
        for (int i = beg + t; i < end; i += 512) {
            unsigned e = ebuf[i];
            int r = atomicAdd(&lcur[(int)(e & 255u)], 1);
            staged[r] = e >> 8;
        }
        __syncthreads();
        for (int i = t; i < cnt; i += 512)
            csr[beg + i] = (int)staged[i];
    } else {
        for (int i = beg + t; i < end; i += 512) {
            unsigned e = ebuf[i];
            int r = atomicAdd(&lcur[(int)(e & 255u)], 1);
            csr[beg + r] = (int)(e >> 8);
        }
    }
}

// ---- fold constants: Wc = Wl1@Wl2 ; Wfold = W2@Wc ; bconst = b2@Wc + bl1@Wl2 + bl2 ----
__global__ __launch_bounds__(256) void k_wfold(const float* __restrict__ W2,
                                               const float* __restrict__ b2,
                                               const float* __restrict__ Wl1,
                                               const float* __restrict__ bl1,
                                               const float* __restrict__ Wl2,
                                               const float* __restrict__ bl2,
                                               float* __restrict__ Wfold,
                                               float* __restrict__ bconst) {
    __shared__ float Wc[64][2];
    __shared__ float bc0[2];
    int t = threadIdx.x;
    if (t < 128) {
        int k = t >> 1, c = t & 1;
        float s = 0.f;
        for (int m = 0; m < 32; ++m) s += Wl1[k * 32 + m] * Wl2[m * 2 + c];
        Wc[k][c] = s;
    } else if (t < 130) {
        int c = t - 128;
        float s = bl2[c];
        for (int m = 0; m < 32; ++m) s += bl1[m] * Wl2[m * 2 + c];
        bc0[c] = s;
    }
    __syncthreads();
    if (t < 128) {
        int k = t >> 1, c = t & 1;
        float s = 0.f;
        for (int j = 0; j < 64; ++j) s += W2[k * 64 + j] * Wc[j][c];
        Wfold[k * 2 + c] = s;
    } else if (t < 130) {
        int c = t - 128;
        float s = bc0[c];
        for (int j = 0; j < 64; ++j) s += b2[j] * Wc[j][c];
        bconst[c] = s;
    }
}

// ---- MFMA GEMM: G[n][64](bf16) = (X[n][K] @ W[K][64]) * dinv[n] ----
template<int K, bool INBF16>
__global__ __launch_bounds__(256) void k_gemm_mfma(const void* __restrict__ Xv,
                                                   const float* __restrict__ W,
                                                   const float* __restrict__ dinv,
                                                   unsigned short* __restrict__ G, int n) {
    constexpr int AST = K + 8;
    __shared__ unsigned short A_lds[64 * AST];
    __shared__ unsigned short Wt_lds[64 * AST];
    __shared__ unsigned short C_lds[64 * 72];
    int t = threadIdx.x;
    int base = blockIdx.x * 64;

    for (int idx = t; idx < K * 64; idx += 256) {
        int k = idx >> 6, nn = idx & 63;
        Wt_lds[nn * AST + k] = f2bf(W[idx]);
    }
    if (!INBF16) {
        const f32x4* X4 = (const f32x4*)Xv;
        constexpr int F4 = K / 4;
        for (int idx = t; idx < 64 * F4; idx += 256) {
            int row = idx / F4, c4 = idx % F4;
            f32x4 f = {0.f, 0.f, 0.f, 0.f};
            if (base + row < n) f = X4[(size_t)base * F4 + idx];
            unsigned p0 = (unsigned)f2bf(f.x) | ((unsigned)f2bf(f.y) << 16);
            unsigned p1 = (unsigned)f2bf(f.z) | ((unsigned)f2bf(f.w) << 16);
            *(uint2*)&A_lds[row * AST + c4 * 4] = make_uint2(p0, p1);
        }
    } else {
        const unsigned* H32 = (const unsigned*)Xv;
        constexpr int U2 = K / 2;
        for (int idx = t; idx < 64 * U2; idx += 256) {
            int row = idx / U2, c2 = idx % U2;
            unsigned u = 0;
            if (base + row < n) u = H32[(size_t)base * U2 + idx];
            *(unsigned*)&A_lds[row * AST + c2 * 2] = u;
        }
    }
    __syncthreads();

    int lane = t & 63, w = t >> 6;
    int q = lane >> 4, m = lane & 15;
    f32x4 acc0 = {0,0,0,0}, acc1 = {0,0,0,0}, acc2 = {0,0,0,0}, acc3 = {0,0,0,0};
    const unsigned short* arow = &A_lds[(16 * w + m) * AST + q * 8];
#pragma unroll
    for (int s = 0; s < K / 32; ++s) {
        short8 a  = *(const short8*)(arow + s * 32);
        short8 w0 = *(const short8*)&Wt_lds[ m       * AST + s * 32 + q * 8];
        short8 w1 = *(const short8*)&Wt_lds[(16 + m) * AST + s * 32 + q * 8];
        short8 w2 = *(const short8*)&Wt_lds[(32 + m) * AST + s * 32 + q * 8];
        short8 w3 = *(const short8*)&Wt_lds[(48 + m) * AST + s * 32 + q * 8];
        acc0 = __builtin_amdgcn_mfma_f32_16x16x32_bf16(a, w0, acc0, 0, 0, 0);
        acc1 = __builtin_amdgcn_mfma_f32_16x16x32_bf16(a, w1, acc1, 0, 0, 0);
        acc2 = __builtin_amdgcn_mfma_f32_16x16x32_bf16(a, w2, acc2, 0, 0, 0);
        acc3 = __builtin_amdgcn_mfma_f32_16x16x32_bf16(a, w3, acc3, 0, 0, 0);
    }
    float dv[4];
#pragma unroll
    for (int r = 0; r < 4; ++r) {
        int node = base + 16 * w + q * 4 + r;
        dv[r] = (node < n) ? dinv[node] : 0.f;
    }
#pragma unroll
    for (int r = 0; r < 4; ++r) {
        int row = 16 * w + q * 4 + r;
        C_lds[row * 72 + m]      = f2bf(acc0[r] * dv[r]);
        C_lds[row * 72 + 16 + m] = f2bf(acc1[r] * dv[r]);
        C_lds[row * 72 + 32 + m] = f2bf(acc2[r] * dv[r]);
        C_lds[row * 72 + 48 + m] = f2bf(acc3[r] * dv[r]);
    }
    __syncthreads();
    for (int idx = t; idx < 4096; idx += 256) {
        int row = idx >> 6, col = idx & 63;
        int node = base + row;
        if (node < n) G[(size_t)node * 64 + col] = C_lds[row * 72 + col];
    }
}

// ---- gather-1 + fused fold: P[w] = dinv[w] * (relu(dinv*(aggr)+b1) @ Wfold) ----
// wave per node; 16-edge unroll keeps 8 independent row-loads in flight
__global__ __launch_bounds__(256) void k_gfold(const int* __restrict__ csr,
                                               const int* __restrict__ offs,
                                               const unsigned short* __restrict__ G,
                                               const float* __restrict__ dinv,
                                               const float* __restrict__ bias,
                                               const float* __restrict__ Wfold,
                                               float2* __restrict__ P, int n) {
    int w = (blockIdx.x * 256 + threadIdx.x) >> 6;
    if (w >= n) return;
    int lane = threadIdx.x & 63;
    int half = lane >> 5, sl = lane & 31;
    const unsigned* Gp = (const unsigned*)G;        // 32 dwords (64 bf16) per row
    float a0 = 0.f, a1 = 0.f;
    if (half == 0) {                                 // self-loop row
        unsigned u = Gp[(size_t)w * 32 + sl];
        a0 = bflo(u); a1 = bfhi(u);
    }
    int beg = offs[w], end = offs[w + 1];
    int e = beg;
    for (; e + 16 <= end; e += 16) {                 // 16 edges: 8 indep row loads
        int s0 = csr[e + half],      s1 = csr[e + 2 + half];
        int s2 = csr[e + 4 + half],  s3 = csr[e + 6 + half];
        int s4 = csr[e + 8 + half],  s5 = csr[e + 10 + half];
        int s6 = csr[e + 12 + half], s7 = csr[e + 14 + half];
        unsigned u0 = Gp[(size_t)s0 * 32 + sl];
        unsigned u1 = Gp[(size_t)s1 * 32 + sl];
        unsigned u2 = Gp[(size_t)s2 * 32 + sl];
        unsigned u3 = Gp[(size_t)s3 * 32 + sl];
        unsigned u4 = Gp[(size_t)s4 * 32 + sl];
        unsigned u5 = Gp[(size_t)s5 * 32 + sl];
        unsigned u6 = Gp[(size_t)s6 * 32 + sl];
        unsigned u7 = Gp[(size_t)s7 * 32 + sl];
        a0 += ((bflo(u0) + bflo(u1)) + (bflo(u2) + bflo(u3)))
            + ((bflo(u4) + bflo(u5)) + (bflo(u6) + bflo(u7)));
        a1 += ((bfhi(u0) + bfhi(u1)) + (bfhi(u2) + bfhi(u3)))
            + ((bfhi(u4) + bfhi(u5)) + (bfhi(u6) + bfhi(u7)));
    }
    for (; e + 8 <= end; e += 8) {                   // 8-edge step (4 loads)
        int s0 = csr[e + half],     s1 = csr[e + 2 + half];
        int s2 = csr[e + 4 + half], s3 = csr[e + 6 + half];
        unsigned u0 = Gp[(size_t)s0 * 32 + sl];
        unsigned u1 = Gp[(size_t)s1 * 32 + sl];
        unsigned u2 = Gp[(size_t)s2 * 32 + sl];
        unsigned u3 = Gp[(size_t)s3 * 32 + sl];
        a0 += (bflo(u0) + bflo(u1)) + (bflo(u2) + bflo(u3));
        a1 += (bfhi(u0) + bfhi(u1)) + (bfhi(u2) + bfhi(u3));
    }
    for (; e + 2 <= end; e += 2) {
        int s = csr[e + half];
        unsigned u = Gp[(size_t)s * 32 + sl];
        a0 += bflo(u); a1 += bfhi(u);
    }
    if (e < end && half == 0) {                      // odd last edge
        int s = csr[e];
        unsigned u = Gp[(size_t)s * 32 + sl];
        a0 += bflo(u); a1 += bfhi(u);
    }
    a0 += __shfl_xor(a0, 32, 64);                    // merge halves
    a1 += __shfl_xor(a1, 32, 64);
    float d = dinv[w];
    float2 bb = ((const float2*)bias)[sl];
    float v0 = fmaxf(fmaf(a0, d, bb.x), 0.f);        // H1[w][2sl]
    float v1 = fmaxf(fmaf(a1, d, bb.y), 0.f);        // H1[w][2sl+1]
    float4 wf = ((const float4*)Wfold)[sl];
    float px = v0 * wf.x + v1 * wf.z;
    float py = v0 * wf.y + v1 * wf.w;
#pragma unroll
    for (int m = 16; m >= 1; m >>= 1) {
        px += __shfl_xor(px, m, 64);
        py += __shfl_xor(py, m, 64);
    }
    if (lane == 0) P[w] = make_float2(px * d, py * d);
}

// ---- gather-2 on P (N x 2, L2-resident) ----
__global__ __launch_bounds__(256) void k_gather2(const int* __restrict__ csr,
                                                 const int* __restrict__ offs,
                                                 const float2* __restrict__ P,
                                                 const float* __restrict__ dinv,
                                                 const float* __restrict__ bconst,
                                                 float* __restrict__ logits, int n) {
    int w = (blockIdx.x * 256 + threadIdx.x) >> 6;
    if (w >= n) return;
    int lane = threadIdx.x & 63;
    int beg = offs[w], end = offs[w + 1];
    float ax = 0.f, ay = 0.f;
    for (int i = beg + lane; i < end; i += 64) {
        float2 p = P[csr[i]];
        ax += p.x; ay += p.y;
    }
#pragma unroll
    for (int m = 32; m >= 1; m >>= 1) {
        ax += __shfl_xor(ax, m, 64);
        ay += __shfl_xor(ay, m, 64);
    }
    if (lane == 0) {
        float2 self = P[w];
        float d = dinv[w];
        logits[w * 2]     = d * (self.x + ax) + bconst[0];
        logits[w * 2 + 1] = d * (self.y + ay) + bconst[1];
    }
}

// ---- parallel softmax, stage 1: per-block (max, sum-exp) partials ----
__global__ __launch_bounds__(256) void k_sm_part(const float* __restrict__ logits,
                                                 float4* __restrict__ partials, int n) {
    __shared__ float r0[256], r1[256];
    int t = threadIdx.x;
    int i = blockIdx.x * 256 + t;
    float l0 = -3.4e38f, l1 = -3.4e38f;
    if (i < n) { l0 = logits[i * 2]; l1 = logits[i * 2 + 1]; }
    r0[t] = l0; r1[t] = l1;
    __syncthreads();
    for (int s = 128; s > 0; s >>= 1) {
        if (t < s) { r0[t] = fmaxf(r0[t], r0[t + s]); r1[t] = fmaxf(r1[t], r1[t + s]); }
        __syncthreads();
    }
    float m0 = r0[0], m1 = r1[0];
    __syncthreads();
    r0[t] = (i < n) ? __expf(l0 - m0) : 0.f;
    r1[t] = (i < n) ? __expf(l1 - m1) : 0.f;
    __syncthreads();
    for (int s = 128; s > 0; s >>= 1) {
        if (t < s) { r0[t] += r0[t + s]; r1[t] += r1[t + s]; }
        __syncthreads();
    }
    if (t == 0) partials[blockIdx.x] = make_float4(m0, r0[0], m1, r1[0]);
}

// ---- stage 2: merge partials -> (M0, invS0, M1, invS1) ----
__global__ __launch_bounds__(512) void k_sm_comb(const float4* __restrict__ partials,
                                                 float4* __restrict__ glob, int nb) {
    __shared__ float m0s[512], s0s[512], m1s[512], s1s[512];
    int t = threadIdx.x;
    float4 p = (t < nb) ? partials[t] : make_float4(-3.4e38f, 0.f, -3.4e38f, 0.f);
    m0s[t] = p.x; m1s[t] = p.z;
    __syncthreads();
    for (int s = 256; s > 0; s >>= 1) {
        if (t < s) { m0s[t] = fmaxf(m0s[t], m0s[t + s]); m1s[t] = fmaxf(m1s[t], m1s[t + s]); }
        __syncthreads();
    }
    float M0 = m0s[0], M1 = m1s[0];
    s0s[t] = (t < nb) ? p.y * __expf(p.x - M0) : 0.f;
    s1s[t] = (t < nb) ? p.w * __expf(p.z - M1) : 0.f;
    __syncthreads();
    for (int s = 256; s > 0; s >>= 1) {
        if (t < s) { s0s[t] += s0s[t + s]; s1s[t] += s1s[t + s]; }
        __syncthreads();
    }
    if (t == 0) *glob = make_float4(M0, 1.f / s0s[0], M1, 1.f / s1s[0]);
}

// ---- stage 3: normalize ----
__global__ __launch_bounds__(256) void k_sm_final(const float* __restrict__ logits,
                                                  const float4* __restrict__ glob,
                                                  float* __restrict__ out, int n) {
    int i = blockIdx.x * 256 + threadIdx.x;
    if (i < n) {
        float4 g = *glob;
        out[i * 2]     = __expf(logits[i * 2]     - g.x) * g.y;
        out[i * 2 + 1] = __expf(logits[i * 2 + 1] - g.z) * g.w;
    }
}

extern "C" void kernel_launch(void* const* d_in, const int* in_sizes, int n_in,
                              void* d_out, int out_size, void* d_ws, size_t ws_size,
                              hipStream_t stream) {
    const float* x   = (const float*)d_in[0];
    const int*   ei  = (const int*)d_in[1];
    const float* W1  = (const float*)d_in[2];
    const float* b1  = (const float*)d_in[3];
    const float* W2  = (const float*)d_in[4];
    const float* b2  = (const float*)d_in[5];
    const float* Wl1 = (const float*)d_in[6];
    const float* bl1 = (const float*)d_in[7];
    const float* Wl2 = (const float*)d_in[8];
    const float* bl2 = (const float*)d_in[9];
    float* out = (float*)d_out;

    int N = in_sizes[0] / F_IN;   // 100000
    int E = in_sizes[1] / 2;      // 3200000
    const int* esrc = ei;
    const int* edst = ei + E;

    int nbuck = (N + 255) / 256;  // 391 coarse buckets of 256 nodes

    char* ws = (char*)d_ws;
    size_t off = 0;
    auto alloc = [&](size_t bytes) { void* p = ws + off; off += (bytes + 255) & ~(size_t)255; return p; };
    int*            bcnt   = (int*)alloc((size_t)NBMAX * 4);
    int*            boff   = (int*)alloc((size_t)(NBMAX + 1) * 4);
    int*            cursor = (int*)alloc((size_t)NBMAX * 4);
    float*          dinv   = (float*)alloc((size_t)N * 4);
    int*            offs   = (int*)alloc((size_t)(N + 1) * 4);
    int*            csr    = (int*)alloc((size_t)E * 4);                 // 12.8 MB
    unsigned*       ebuf   = (unsigned*)alloc((size_t)E * 4);            // 12.8 MB
    unsigned short* gbuf   = (unsigned short*)alloc((size_t)N * 64 * 2); // 12.8 MB bf16
    float*          Wfold  = (float*)alloc(64 * 2 * 4);
    float*          bconst = (float*)alloc(2 * 4);
    float2*         P      = (float2*)alloc((size_t)N * 8);              // 800 KB
    float*          logits = (float*)alloc((size_t)N * 2 * 4);           // 800 KB
    float4*         smpart = (float4*)alloc((size_t)NBMAX * 16);
    float4*         smglob = (float4*)alloc(16);

    hipMemsetAsync(bcnt, 0, NBMAX * sizeof(int), stream);

    int tiles = (E + TILE1 - 1) / TILE1;   // 391
    int mb = (N + 63) / 64;
    int wb = (N * 64 + 255) / 256;         // wave-per-node grids
    int nb = (N + 255) / 256;

    // CSR build
    k_cnt<<<tiles, 256, 0, stream>>>(edst, E, bcnt, nbuck);
    k_bscan1<<<1, 512, 0, stream>>>(bcnt, boff, cursor, nbuck);
    k_part1<<<tiles, 512, 0, stream>>>(esrc, edst, cursor, ebuf, E, nbuck);
    k_part2<<<nbuck, 512, 0, stream>>>(ebuf, boff, csr, offs, dinv, N);

    // constant folding: Wfold = W2@Wl1@Wl2 ; bconst = b2@Wc + bl1@Wl2 + bl2
    k_wfold<<<1, 256, 0, stream>>>(W2, b2, Wl1, bl1, Wl2, bl2, Wfold, bconst);

    // layer 1 GEMM: G1 = bf16((x@W1)*dinv)
    k_gemm_mfma<128, false><<<mb, 256, 0, stream>>>(x, W1, dinv, gbuf, N);

    // gather-1 + relu + fold: P = dinv * (relu(dinv*(G1[d]+sum G1[src]) + b1) @ Wfold)
    k_gfold<<<wb, 256, 0, stream>>>(csr, offs, gbuf, dinv, b1, Wfold, P, N);

    // gather-2 on P -> logits
    k_gather2<<<wb, 256, 0, stream>>>(csr, offs, P, dinv, bconst, logits, N);

    // parallel softmax over nodes
    k_sm_part<<<nb, 256, 0, stream>>>(logits, smpart, N);
    k_sm_comb<<<1, 512, 0, stream>>>(smpart, smglob, nb);
    k_sm_final<<<nb, 256, 0, stream>>>(logits, smglob, out, N);
}

// Round 14
// 281.726 us; speedup vs baseline: 1.2832x; 1.0293x over previous
//
#include <hip/hip_runtime.h>

#define F_IN 128
#define NBMAX 512      // max coarse buckets (256 nodes each)
#define TILE1 8192     // edges per partition tile
#define CAP2 10240     // pass-2 LDS staging capacity

typedef __attribute__((ext_vector_type(8))) short short8;
typedef __attribute__((ext_vector_type(4))) float f32x4;

__device__ __forceinline__ unsigned short f2bf(float f) {   // RNE float->bf16
    unsigned u = __float_as_uint(f);
    u += 0x7fffu + ((u >> 16) & 1u);
    return (unsigned short)(u >> 16);
}
__device__ __forceinline__ float bflo(unsigned u) { return __uint_as_float(u << 16); }
__device__ __forceinline__ float bfhi(unsigned u) { return __uint_as_float(u & 0xffff0000u); }

// ---- coarse-bucket histogram: bcnt[dst>>8] += 1, LDS-staged ----
__global__ __launch_bounds__(512) void k_cnt(const int* __restrict__ dst, int E,
                                             int* __restrict__ bcnt, int nb) {
    __shared__ int h[NBMAX];
    int t = threadIdx.x;
    for (int i = t; i < nb; i += 512) h[i] = 0;
    __syncthreads();
    int base = blockIdx.x * TILE1;
    int end = min(base + TILE1, E);
    for (int i = base + t; i < end; i += 512)
        atomicAdd(&h[dst[i] >> 8], 1);
    __syncthreads();
    for (int i = t; i < nb; i += 512)
        if (h[i]) atomicAdd(&bcnt[i], h[i]);
}

// ---- exclusive scan of bucket counts (nb <= 512), single block ----
__global__ __launch_bounds__(512) void k_bscan1(const int* __restrict__ bcnt,
                                                int* __restrict__ boff,
                                                int* __restrict__ cursor, int nb) {
    __shared__ int part[512];
    int t = threadIdx.x;
    int v = (t < nb) ? bcnt[t] : 0;
    part[t] = v;
    __syncthreads();
    for (int d = 1; d < 512; d <<= 1) {
        int u = (t >= d) ? part[t - d] : 0;
        __syncthreads();
        part[t] += u;
        __syncthreads();
    }
    if (t < nb) { boff[t] = part[t] - v; cursor[t] = part[t] - v; }
    if (t == 511) boff[nb] = part[511];   // == E
}

// ---- pass 1: LDS-staged partition into coarse buckets; burst writes ----
// 1024 threads: grid is ~1.5 blocks/CU, so waves/block is the parallelism lever
__global__ __launch_bounds__(1024) void k_part1(const int* __restrict__ src,
                                                const int* __restrict__ dst,
                                                int* __restrict__ cursor,
                                                unsigned* __restrict__ ebuf,
                                                int E, int nb) {
    __shared__ unsigned staged[TILE1];
    __shared__ unsigned short sbuck[TILE1];
    __shared__ int hist[NBMAX], lbase[NBMAX], lcur[NBMAX], gbase[NBMAX];
    int t = threadIdx.x;
    for (int i = t; i < nb; i += 1024) hist[i] = 0;
    __syncthreads();
    int base = blockIdx.x * TILE1;
    int end = min(base + TILE1, E);
    for (int i = base + t; i < end; i += 1024)
        atomicAdd(&hist[dst[i] >> 8], 1);
    __syncthreads();
    if (t < 64) {                                // single-wave chunked scan
        int carry = 0;
        for (int c = 0; c < (nb + 63) / 64; ++c) {
            int idx = c * 64 + t;
            int v = (idx < nb) ? hist[idx] : 0;
            int inc = v;
            for (int d = 1; d < 64; d <<= 1) {
                int u = __shfl_up(inc, d, 64);
                if (t >= d) inc += u;
            }
            if (idx < nb) { int ex = carry + inc - v; lbase[idx] = ex; lcur[idx] = ex; }
            carry += __shfl(inc, 63, 64);
        }
    }
    __syncthreads();
    for (int i = t; i < nb; i += 1024)
        gbase[i] = hist[i] ? atomicAdd(&cursor[i], hist[i]) : 0;
    for (int i = base + t; i < end; i += 1024) {
        int d = dst[i];
        int b = d >> 8;
        int r = atomicAdd(&lcur[b], 1);
        staged[r] = ((unsigned)src[i] << 8) | (unsigned)(d & 255);
        sbuck[r] = (unsigned short)b;
    }
    __syncthreads();
    int cnt = end - base;
    for (int i = t; i < cnt; i += 1024) {
        int b = sbuck[i];
        ebuf[gbase[b] + (i - lbase[b])] = staged[i];
    }
}

// ---- pass 2: per-bucket 256-bin counting sort; emits csr, offs, dinv ----
__global__ __launch_bounds__(1024) void k_part2(const unsigned* __restrict__ ebuf,
                                                const int* __restrict__ boff,
                                                int* __restrict__ csr,
                                                int* __restrict__ offs,
                                                float* __restrict__ dinv, int n) {
    __shared__ unsigned staged[CAP2];
    __shared__ int hist[256], lcur[256];
    int t = threadIdx.x;
    int b = blockIdx.x;
    int beg = boff[b], end = boff[b + 1];
    int cnt = end - beg;
    if (t < 256) hist[t] = 0;
    __syncthreads();
    for (int i = beg + t; i < end; i += 1024)
        atomicAdd(&hist[ebuf[i] & 255u], 1);
    __syncthreads();
    if (t < 64) {
        int carry = 0;
        for (int c = 0; c < 4; ++c) {
            int idx = c * 64 + t;
            int v = hist[idx];
            int inc = v;
            for (int d = 1; d < 64; d <<= 1) {
                int u = __shfl_up(inc, d, 64);
                if (t >= d) inc += u;
            }
            int ex = carry + inc - v;
            lcur[idx] = ex;
            int node = b * 256 + idx;
            if (node <= n) offs[node] = beg + ex;
            if (node < n) dinv[node] = rsqrtf((float)(v + 1));
            carry += __shfl(inc, 63, 64);
        }
    }
    __syncthreads();
    if (cnt <= CAP2) {
        for (int i = beg + t; i < end; i += 1024) {
            unsigned e = ebuf[i];
            int r = atomicAdd(&lcur[(int)(e & 255u)], 1);
            staged[r] = e >> 8;
        }
        __syncthreads();
        for (int i = t; i < cnt; i += 1024)
            csr[beg + i] = (int)staged[i];
    } else {
        for (int i = beg + t; i < end; i += 1024) {
            unsigned e = ebuf[i];
            int r = atomicAdd(&lcur[(int)(e & 255u)], 1);
            csr[beg + r] = (int)(e >> 8);
        }
    }
}

// ---- fold constants: Wc = Wl1@Wl2 ; Wfold = W2@Wc ; bconst = b2@Wc + bl1@Wl2 + bl2 ----
__global__ __launch_bounds__(256) void k_wfold(const float* __restrict__ W2,
                                               const float* __restrict__ b2,
                                               const float* __restrict__ Wl1,
                                               const float* __restrict__ bl1,
                                               const float* __restrict__ Wl2,
                                               const float* __restrict__ bl2,
                                               float* __restrict__ Wfold,
                                               float* __restrict__ bconst) {
    __shared__ float Wc[64][2];
    __shared__ float bc0[2];
    int t = threadIdx.x;
    if (t < 128) {
        int k = t >> 1, c = t & 1;
        float s = 0.f;
        for (int m = 0; m < 32; ++m) s += Wl1[k * 32 + m] * Wl2[m * 2 + c];
        Wc[k][c] = s;
    } else if (t < 130) {
        int c = t - 128;
        float s = bl2[c];
        for (int m = 0; m < 32; ++m) s += bl1[m] * Wl2[m * 2 + c];
        bc0[c] = s;
    }
    __syncthreads();
    if (t < 128) {
        int k = t >> 1, c = t & 1;
        float s = 0.f;
        for (int j = 0; j < 64; ++j) s += W2[k * 64 + j] * Wc[j][c];
        Wfold[k * 2 + c] = s;
    } else if (t < 130) {
        int c = t - 128;
        float s = bc0[c];
        for (int j = 0; j < 64; ++j) s += b2[j] * Wc[j][c];
        bconst[c] = s;
    }
}

// ---- MFMA GEMM: G[n][64](bf16) = (X[n][K] @ W[K][64]) * dinv[n] ----
template<int K, bool INBF16>
__global__ __launch_bounds__(256) void k_gemm_mfma(const void* __restrict__ Xv,
                                                   const float* __restrict__ W,
                                                   const float* __restrict__ dinv,
                                                   unsigned short* __restrict__ G, int n) {
    constexpr int AST = K + 8;
    __shared__ unsigned short A_lds[64 * AST];
    __shared__ unsigned short Wt_lds[64 * AST];
    __shared__ unsigned short C_lds[64 * 72];
    int t = threadIdx.x;
    int base = blockIdx.x * 64;

    for (int idx = t; idx < K * 64; idx += 256) {
        int k = idx >> 6, nn = idx & 63;
        Wt_lds[nn * AST + k] = f2bf(W[idx]);
    }
    if (!INBF16) {
        const f32x4* X4 = (const f32x4*)Xv;
        constexpr int F4 = K / 4;
        for (int idx = t; idx < 64 * F4; idx += 256) {
            int row = idx / F4, c4 = idx % F4;
            f32x4 f = {0.f, 0.f, 0.f, 0.f};
            if (base + row < n) f = X4[(size_t)base * F4 + idx];
            unsigned p0 = (unsigned)f2bf(f.x) | ((unsigned)f2bf(f.y) << 16);
            unsigned p1 = (unsigned)f2bf(f.z) | ((unsigned)f2bf(f.w) << 16);
            *(uint2*)&A_lds[row * AST + c4 * 4] = make_uint2(p0, p1);
        }
    } else {
        const unsigned* H32 = (const unsigned*)Xv;
        constexpr int U2 = K / 2;
        for (int idx = t; idx < 64 * U2; idx += 256) {
            int row = idx / U2, c2 = idx % U2;
            unsigned u = 0;
            if (base + row < n) u = H32[(size_t)base * U2 + idx];
            *(unsigned*)&A_lds[row * AST + c2 * 2] = u;
        }
    }
    __syncthreads();

    int lane = t & 63, w = t >> 6;
    int q = lane >> 4, m = lane & 15;
    f32x4 acc0 = {0,0,0,0}, acc1 = {0,0,0,0}, acc2 = {0,0,0,0}, acc3 = {0,0,0,0};
    const unsigned short* arow = &A_lds[(16 * w + m) * AST + q * 8];
#pragma unroll
    for (int s = 0; s < K / 32; ++s) {
        short8 a  = *(const short8*)(arow + s * 32);
        short8 w0 = *(const short8*)&Wt_lds[ m       * AST + s * 32 + q * 8];
        short8 w1 = *(const short8*)&Wt_lds[(16 + m) * AST + s * 32 + q * 8];
        short8 w2 = *(const short8*)&Wt_lds[(32 + m) * AST + s * 32 + q * 8];
        short8 w3 = *(const short8*)&Wt_lds[(48 + m) * AST + s * 32 + q * 8];
        acc0 = __builtin_amdgcn_mfma_f32_16x16x32_bf16(a, w0, acc0, 0, 0, 0);
        acc1 = __builtin_amdgcn_mfma_f32_16x16x32_bf16(a, w1, acc1, 0, 0, 0);
        acc2 = __builtin_amdgcn_mfma_f32_16x16x32_bf16(a, w2, acc2, 0, 0, 0);
        acc3 = __builtin_amdgcn_mfma_f32_16x16x32_bf16(a, w3, acc3, 0, 0, 0);
    }
    float dv[4];
#pragma unroll
    for (int r = 0; r < 4; ++r) {
        int node = base + 16 * w + q * 4 + r;
        dv[r] = (node < n) ? dinv[node] : 0.f;
    }
#pragma unroll
    for (int r = 0; r < 4; ++r) {
        int row = 16 * w + q * 4 + r;
        C_lds[row * 72 + m]      = f2bf(acc0[r] * dv[r]);
        C_lds[row * 72 + 16 + m] = f2bf(acc1[r] * dv[r]);
        C_lds[row * 72 + 32 + m] = f2bf(acc2[r] * dv[r]);
        C_lds[row * 72 + 48 + m] = f2bf(acc3[r] * dv[r]);
    }
    __syncthreads();
    for (int idx = t; idx < 4096; idx += 256) {
        int row = idx >> 6, col = idx & 63;
        int node = base + row;
        if (node < n) G[(size_t)node * 64 + col] = C_lds[row * 72 + col];
    }
}

// ---- gather-1 + fused fold; 16-edge unroll, csr indices prefetched one iter ahead ----
__global__ __launch_bounds__(256) void k_gfold(const int* __restrict__ csr,
                                               const int* __restrict__ offs,
                                               const unsigned short* __restrict__ G,
                                               const float* __restrict__ dinv,
                                               const float* __restrict__ bias,
                                               const float* __restrict__ Wfold,
                                               float2* __restrict__ P, int n) {
    int w = (blockIdx.x * 256 + threadIdx.x) >> 6;
    if (w >= n) return;
    int lane = threadIdx.x & 63;
    int half = lane >> 5, sl = lane & 31;
    const unsigned* Gp = (const unsigned*)G;        // 32 dwords (64 bf16) per row
    float a0 = 0.f, a1 = 0.f;
    if (half == 0) {                                 // self-loop row
        unsigned u = Gp[(size_t)w * 32 + sl];
        a0 = bflo(u); a1 = bfhi(u);
    }
    int beg = offs[w], end = offs[w + 1];
    int e = beg;
    int c0 = 0, c1 = 0, c2 = 0, c3 = 0, c4 = 0, c5 = 0, c6 = 0, c7 = 0;
    if (e + 16 <= end) {
        c0 = csr[e + half];      c1 = csr[e + 2 + half];
        c2 = csr[e + 4 + half];  c3 = csr[e + 6 + half];
        c4 = csr[e + 8 + half];  c5 = csr[e + 10 + half];
        c6 = csr[e + 12 + half]; c7 = csr[e + 14 + half];
    }
    while (e + 16 <= end) {                          // 16 edges: 8 indep row loads
        unsigned u0 = Gp[(size_t)c0 * 32 + sl];
        unsigned u1 = Gp[(size_t)c1 * 32 + sl];
        unsigned u2 = Gp[(size_t)c2 * 32 + sl];
        unsigned u3 = Gp[(size_t)c3 * 32 + sl];
        unsigned u4 = Gp[(size_t)c4 * 32 + sl];
        unsigned u5 = Gp[(size_t)c5 * 32 + sl];
        unsigned u6 = Gp[(size_t)c6 * 32 + sl];
        unsigned u7 = Gp[(size_t)c7 * 32 + sl];
        int ne = e + 16;
        if (ne + 16 <= end) {                        // prefetch next iter's csr
            c0 = csr[ne + half];      c1 = csr[ne + 2 + half];
            c2 = csr[ne + 4 + half];  c3 = csr[ne + 6 + half];
            c4 = csr[ne + 8 + half];  c5 = csr[ne + 10 + half];
            c6 = csr[ne + 12 + half]; c7 = csr[ne + 14 + half];
        }
        a0 += ((bflo(u0) + bflo(u1)) + (bflo(u2) + bflo(u3)))
            + ((bflo(u4) + bflo(u5)) + (bflo(u6) + bflo(u7)));
        a1 += ((bfhi(u0) + bfhi(u1)) + (bfhi(u2) + bfhi(u3)))
            + ((bfhi(u4) + bfhi(u5)) + (bfhi(u6) + bfhi(u7)));
        e = ne;
    }
    for (; e + 8 <= end; e += 8) {                   // 8-edge step (4 loads)
        int s0 = csr[e + half],     s1 = csr[e + 2 + half];
        int s2 = csr[e + 4 + half], s3 = csr[e + 6 + half];
        unsigned u0 = Gp[(size_t)s0 * 32 + sl];
        unsigned u1 = Gp[(size_t)s1 * 32 + sl];
        unsigned u2 = Gp[(size_t)s2 * 32 + sl];
        unsigned u3 = Gp[(size_t)s3 * 32 + sl];
        a0 += (bflo(u0) + bflo(u1)) + (bflo(u2) + bflo(u3));
        a1 += (bfhi(u0) + bfhi(u1)) + (bfhi(u2) + bfhi(u3));
    }
    for (; e + 2 <= end; e += 2) {
        int s = csr[e + half];
        unsigned u = Gp[(size_t)s * 32 + sl];
        a0 += bflo(u); a1 += bfhi(u);
    }
    if (e < end && half == 0) {                      // odd last edge
        int s = csr[e];
        unsigned u = Gp[(size_t)s * 32 + sl];
        a0 += bflo(u); a1 += bfhi(u);
    }
    a0 += __shfl_xor(a0, 32, 64);                    // merge halves
    a1 += __shfl_xor(a1, 32, 64);
    float d = dinv[w];
    float2 bb = ((const float2*)bias)[sl];
    float v0 = fmaxf(fmaf(a0, d, bb.x), 0.f);        // H1[w][2sl]
    float v1 = fmaxf(fmaf(a1, d, bb.y), 0.f);        // H1[w][2sl+1]
    float4 wf = ((const float4*)Wfold)[sl];
    float px = v0 * wf.x + v1 * wf.z;
    float py = v0 * wf.y + v1 * wf.w;
#pragma unroll
    for (int m = 16; m >= 1; m >>= 1) {
        px += __shfl_xor(px, m, 64);
        py += __shfl_xor(py, m, 64);
    }
    if (lane == 0) P[w] = make_float2(px * d, py * d);
}

// ---- gather-2 on P (N x 2, L2-resident) ----
__global__ __launch_bounds__(256) void k_gather2(const int* __restrict__ csr,
                                                 const int* __restrict__ offs,
                                                 const float2* __restrict__ P,
                                                 const float* __restrict__ dinv,
                                                 const float* __restrict__ bconst,
                                                 float* __restrict__ logits, int n) {
    int w = (blockIdx.x * 256 + threadIdx.x) >> 6;
    if (w >= n) return;
    int lane = threadIdx.x & 63;
    int beg = offs[w], end = offs[w + 1];
    float ax = 0.f, ay = 0.f;
    for (int i = beg + lane; i < end; i += 64) {
        float2 p = P[csr[i]];
        ax += p.x; ay += p.y;
    }
#pragma unroll
    for (int m = 32; m >= 1; m >>= 1) {
        ax += __shfl_xor(ax, m, 64);
        ay += __shfl_xor(ay, m, 64);
    }
    if (lane == 0) {
        float2 self = P[w];
        float d = dinv[w];
        logits[w * 2]     = d * (self.x + ax) + bconst[0];
        logits[w * 2 + 1] = d * (self.y + ay) + bconst[1];
    }
}

// ---- parallel softmax, stage 1: per-block (max, sum-exp) partials ----
__global__ __launch_bounds__(256) void k_sm_part(const float* __restrict__ logits,
                                                 float4* __restrict__ partials, int n) {
    __shared__ float r0[256], r1[256];
    int t = threadIdx.x;
    int i = blockIdx.x * 256 + t;
    float l0 = -3.4e38f, l1 = -3.4e38f;
    if (i < n) { l0 = logits[i * 2]; l1 = logits[i * 2 + 1]; }
    r0[t] = l0; r1[t] = l1;
    __syncthreads();
    for (int s = 128; s > 0; s >>= 1) {
        if (t < s) { r0[t] = fmaxf(r0[t], r0[t + s]); r1[t] = fmaxf(r1[t], r1[t + s]); }
        __syncthreads();
    }
    float m0 = r0[0], m1 = r1[0];
    __syncthreads();
    r0[t] = (i < n) ? __expf(l0 - m0) : 0.f;
    r1[t] = (i < n) ? __expf(l1 - m1) : 0.f;
    __syncthreads();
    for (int s = 128; s > 0; s >>= 1) {
        if (t < s) { r0[t] += r0[t + s]; r1[t] += r1[t + s]; }
        __syncthreads();
    }
    if (t == 0) partials[blockIdx.x] = make_float4(m0, r0[0], m1, r1[0]);
}

// ---- stage 2: merge partials -> (M0, invS0, M1, invS1) ----
__global__ __launch_bounds__(512) void k_sm_comb(const float4* __restrict__ partials,
                                                 float4* __restrict__ glob, int nb) {
    __shared__ float m0s[512], s0s[512], m1s[512], s1s[512];
    int t = threadIdx.x;
    float4 p = (t < nb) ? partials[t] : make_float4(-3.4e38f, 0.f, -3.4e38f, 0.f);
    m0s[t] = p.x; m1s[t] = p.z;
    __syncthreads();
    for (int s = 256; s > 0; s >>= 1) {
        if (t < s) { m0s[t] = fmaxf(m0s[t], m0s[t + s]); m1s[t] = fmaxf(m1s[t], m1s[t + s]); }
        __syncthreads();
    }
    float M0 = m0s[0], M1 = m1s[0];
    s0s[t] = (t < nb) ? p.y * __expf(p.x - M0) : 0.f;
    s1s[t] = (t < nb) ? p.w * __expf(p.z - M1) : 0.f;
    __syncthreads();
    for (int s = 256; s > 0; s >>= 1) {
        if (t < s) { s0s[t] += s0s[t + s]; s1s[t] += s1s[t + s]; }
        __syncthreads();
    }
    if (t == 0) *glob = make_float4(M0, 1.f / s0s[0], M1, 1.f / s1s[0]);
}

// ---- stage 3: normalize ----
__global__ __launch_bounds__(256) void k_sm_final(const float* __restrict__ logits,
                                                  const float4* __restrict__ glob,
                                                  float* __restrict__ out, int n) {
    int i = blockIdx.x * 256 + threadIdx.x;
    if (i < n) {
        float4 g = *glob;
        out[i * 2]     = __expf(logits[i * 2]     - g.x) * g.y;
        out[i * 2 + 1] = __expf(logits[i * 2 + 1] - g.z) * g.w;
    }
}

extern "C" void kernel_launch(void* const* d_in, const int* in_sizes, int n_in,
                              void* d_out, int out_size, void* d_ws, size_t ws_size,
                              hipStream_t stream) {
    const float* x   = (const float*)d_in[0];
    const int*   ei  = (const int*)d_in[1];
    const float* W1  = (const float*)d_in[2];
    const float* b1  = (const float*)d_in[3];
    const float* W2  = (const float*)d_in[4];
    const float* b2  = (const float*)d_in[5];
    const float* Wl1 = (const float*)d_in[6];
    const float* bl1 = (const float*)d_in[7];
    const float* Wl2 = (const float*)d_in[8];
    const float* bl2 = (const float*)d_in[9];
    float* out = (float*)d_out;

    int N = in_sizes[0] / F_IN;   // 100000
    int E = in_sizes[1] / 2;      // 3200000
    const int* esrc = ei;
    const int* edst = ei + E;

    int nbuck = (N + 255) / 256;  // 391 coarse buckets of 256 nodes

    char* ws = (char*)d_ws;
    size_t off = 0;
    auto alloc = [&](size_t bytes) { void* p = ws + off; off += (bytes + 255) & ~(size_t)255; return p; };
    int*            bcnt   = (int*)alloc((size_t)NBMAX * 4);
    int*            boff   = (int*)alloc((size_t)(NBMAX + 1) * 4);
    int*            cursor = (int*)alloc((size_t)NBMAX * 4);
    float*          dinv   = (float*)alloc((size_t)N * 4);
    int*            offs   = (int*)alloc((size_t)(N + 1) * 4);
    int*            csr    = (int*)alloc((size_t)E * 4);                 // 12.8 MB
    unsigned*       ebuf   = (unsigned*)alloc((size_t)E * 4);            // 12.8 MB
    unsigned short* gbuf   = (unsigned short*)alloc((size_t)N * 64 * 2); // 12.8 MB bf16
    float*          Wfold  = (float*)alloc(64 * 2 * 4);
    float*          bconst = (float*)alloc(2 * 4);
    float2*         P      = (float2*)alloc((size_t)N * 8);              // 800 KB
    float*          logits = (float*)alloc((size_t)N * 2 * 4);           // 800 KB
    float4*         smpart = (float4*)alloc((size_t)NBMAX * 16);
    float4*         smglob = (float4*)alloc(16);

    hipMemsetAsync(bcnt, 0, NBMAX * sizeof(int), stream);

    int tiles = (E + TILE1 - 1) / TILE1;   // 391
    int mb = (N + 63) / 64;
    int wb = (N * 64 + 255) / 256;         // wave-per-node grids
    int nb = (N + 255) / 256;

    // CSR build
    k_cnt<<<tiles, 512, 0, stream>>>(edst, E, bcnt, nbuck);
    k_bscan1<<<1, 512, 0, stream>>>(bcnt, boff, cursor, nbuck);
    k_part1<<<tiles, 1024, 0, stream>>>(esrc, edst, cursor, ebuf, E, nbuck);
    k_part2<<<nbuck, 1024, 0, stream>>>(ebuf, boff, csr, offs, dinv, N);

    // constant folding: Wfold = W2@Wl1@Wl2 ; bconst = b2@Wc + bl1@Wl2 + bl2
    k_wfold<<<1, 256, 0, stream>>>(W2, b2, Wl1, bl1, Wl2, bl2, Wfold, bconst);

    // layer 1 GEMM: G1 = bf16((x@W1)*dinv)
    k_gemm_mfma<128, false><<<mb, 256, 0, stream>>>(x, W1, dinv, gbuf, N);

    // gather-1 + relu + fold: P = dinv * (relu(dinv*(G1[d]+sum G1[src]) + b1) @ Wfold)
    k_gfold<<<wb, 256, 0, stream>>>(csr, offs, gbuf, dinv, b1, Wfold, P, N);

    // gather-2 on P -> logits
    k_gather2<<<wb, 256, 0, stream>>>(csr, offs, P, dinv, bconst, logits, N);

    // parallel softmax over nodes
    k_sm_part<<<nb, 256, 0, stream>>>(logits, smpart, N);
    k_sm_comb<<<1, 512, 0, stream>>>(smpart, smglob, nb);
    k_sm_final<<<nb, 256, 0, stream>>>(logits, smglob, out, N);
}